// Round 1
// baseline (258.628 us; speedup 1.0000x reference)
//
#include <hip/hip_runtime.h>

// QuantizedAdd: out = clip(requant(bypass) + requant(prev) + z3, -128, 127)
// B=128, C=64, H=56, W=56  -> CHW = 200704 (divisible by 4*256 = 1024)
// All inputs int32; output int32 (clipped int8 range).
//
// Memory-bound elementwise: 2 reads + 1 write of 102.8 MB each.
// int4 vectorization: 16B per lane. Per-sample params are uniform per
// blockIdx.y -> scalar loads + scalar branch folding (lsh/rsh).

constexpr int kCHW  = 64 * 56 * 56;   // 200704
constexpr int kCHW4 = kCHW / 4;       // 50176 = 196 * 256

// gemmlowp requantize with pre-split shifts (lsh = left-shift when shift<0,
// rsh = rounding-divide shift when shift>=0; exactly one of them nonzero or both 0).
__device__ __forceinline__ long long requant_one(int x, int z, long long M0,
                                                 int lsh, int rsh) {
    long long v = ((long long)(x - z)) << lsh;
    // SaturatingRoundingDoublingHighMul: ((v*M0) + nudge) >> 31
    long long prod = v * M0;
    long long nudge = (prod >= 0) ? (1LL << 30) : (1LL - (1LL << 30));
    long long r = (prod + nudge) >> 31;   // arithmetic shift (impl-defined but AMD/clang: arithmetic)
    // RoundingDivideByPOT by rsh (rsh >= 0); rsh==0 is a no-op by construction:
    long long mask = (1LL << rsh) - 1;
    long long rem = r & mask;
    long long thr = (mask >> 1) + ((r < 0) ? 1LL : 0LL);
    return (r >> rsh) + ((rem > thr) ? 1LL : 0LL);
}

__global__ __launch_bounds__(256) void QuantizedAdd_kernel(
    const int* __restrict__ bypass, const int* __restrict__ prev,
    const int* __restrict__ batch_cluster,
    const int* __restrict__ z_bypass, const int* __restrict__ z_prev,
    const int* __restrict__ z3,
    const int* __restrict__ M0_bypass, const int* __restrict__ M0_prev,
    const int* __restrict__ shift_bypass, const int* __restrict__ shift_prev,
    int* __restrict__ out)
{
    const int b = blockIdx.y;                 // sample index, uniform per block
    const int c = batch_cluster[b];           // cluster index, uniform -> scalar load

    const int       zb  = z_bypass[c];
    const int       zp  = z_prev[c];
    const int       z3v = z3[c];
    const long long M0b = (long long)M0_bypass[c];
    const long long M0p = (long long)M0_prev[c];
    const int       sb  = shift_bypass[c];
    const int       sp  = shift_prev[c];
    const int lsh_b = (sb < 0) ? -sb : 0;
    const int rsh_b = (sb < 0) ?   0 : sb;
    const int lsh_p = (sp < 0) ? -sp : 0;
    const int rsh_p = (sp < 0) ?   0 : sp;

    // Flat int4 index: fits comfortably in 32 bits (max ~6.4M).
    const int idx4 = b * kCHW4 + blockIdx.x * 256 + threadIdx.x;

    const int4 xb = ((const int4*)bypass)[idx4];
    const int4 xp = ((const int4*)prev)[idx4];

    int4 o;
    {
        long long t;
        t = requant_one(xb.x, zb, M0b, lsh_b, rsh_b)
          + requant_one(xp.x, zp, M0p, lsh_p, rsh_p) + (long long)z3v;
        o.x = (int)(t < -128 ? -128 : (t > 127 ? 127 : t));
        t = requant_one(xb.y, zb, M0b, lsh_b, rsh_b)
          + requant_one(xp.y, zp, M0p, lsh_p, rsh_p) + (long long)z3v;
        o.y = (int)(t < -128 ? -128 : (t > 127 ? 127 : t));
        t = requant_one(xb.z, zb, M0b, lsh_b, rsh_b)
          + requant_one(xp.z, zp, M0p, lsh_p, rsh_p) + (long long)z3v;
        o.z = (int)(t < -128 ? -128 : (t > 127 ? 127 : t));
        t = requant_one(xb.w, zb, M0b, lsh_b, rsh_b)
          + requant_one(xp.w, zp, M0p, lsh_p, rsh_p) + (long long)z3v;
        o.w = (int)(t < -128 ? -128 : (t > 127 ? 127 : t));
    }

    ((int4*)out)[idx4] = o;
}

extern "C" void kernel_launch(void* const* d_in, const int* in_sizes, int n_in,
                              void* d_out, int out_size, void* d_ws, size_t ws_size,
                              hipStream_t stream) {
    const int* bypass        = (const int*)d_in[0];
    const int* prev          = (const int*)d_in[1];
    const int* batch_cluster = (const int*)d_in[2];
    const int* z_bypass      = (const int*)d_in[3];
    const int* z_prev        = (const int*)d_in[4];
    const int* z3            = (const int*)d_in[5];
    const int* M0_bypass     = (const int*)d_in[6];
    const int* M0_prev       = (const int*)d_in[7];
    const int* shift_bypass  = (const int*)d_in[8];
    const int* shift_prev    = (const int*)d_in[9];

    const int B = in_sizes[2];                  // 128
    dim3 grid(kCHW4 / 256, B, 1);               // (196, 128)
    dim3 block(256, 1, 1);
    QuantizedAdd_kernel<<<grid, block, 0, stream>>>(
        bypass, prev, batch_cluster, z_bypass, z_prev, z3,
        M0_bypass, M0_prev, shift_bypass, shift_prev, (int*)d_out);
}